// Round 1
// 486.068 us; speedup vs baseline: 1.0329x; 1.0329x over previous
//
#include <hip/hip_runtime.h>
#include <math.h>
#include <stdint.h>

// ---------------------------------------------------------------------------
// MultiHeadAttention, softmax over HEAD axis (dim=1), bf16 MFMA pipeline.
// B=4, S=2048, DIM=1024, H=8, DH=128.
//   q = (Q WQ^T) * 1/sqrt(128)   [b,s,1024] bf16 (scale folded in epilogue)
//   k =  K WK^T                  [b,s,1024] bf16
//   vt = (V WV^T) transposed ->  [b,h,dh,s] bf16 (epilogue transpose)
//   P[bloc,h,q,k] = exp(sT)/sum_h exp  via qk_head_softmax v4:
//     64k x 128q tile; TWO passes over heads (recompute QK on pass 2 --
//     MFMA is cheap, registers are not). v4: BK=64 staging (16 MFMA per
//     barrier-pair, halves barrier count) + XOR-swizzled LDS everywhere
//     (linear cp16 dest, inverse-swizzled GLOBAL source, swizzled reads).
//   P chunked at 134 MB (nb=4, C=1024) -> chunk stays L3-resident between
//   qk and pv (no HBM round-trip for P).
//   ctx = P·V via pv_gemm (128dh x 64q tiles -> 512 blocks per chunk),
//   out = ctx WO^T fp32 -> d_out
// ---------------------------------------------------------------------------

typedef __attribute__((ext_vector_type(8))) __bf16 bf16x8;
typedef __attribute__((ext_vector_type(4))) __bf16 bf16x4;
typedef __attribute__((ext_vector_type(4))) float  f32x4;

__device__ __forceinline__ f32x4 mfma16(bf16x8 a, bf16x8 b, f32x4 c) {
    return __builtin_amdgcn_mfma_f32_16x16x32_bf16(a, b, c, 0, 0, 0);
}

// async global->LDS, 16B per lane; LDS dest must be wave-uniform-base + lane*16
__device__ __forceinline__ void cp16(void* lds, const void* g) {
    __builtin_amdgcn_global_load_lds(
        (__attribute__((address_space(1))) void*)(void*)(const_cast<void*>(g)),
        (__attribute__((address_space(3))) void*)lds,
        16, 0, 0);
}

// ---------------------------------------------------------------------------
// 4 weight tensors in one launch
__global__ void cast4_f32_to_bf16(const float* __restrict__ s0, __bf16* __restrict__ d0,
                                  const float* __restrict__ s1, __bf16* __restrict__ d1,
                                  const float* __restrict__ s2, __bf16* __restrict__ d2,
                                  const float* __restrict__ s3, __bf16* __restrict__ d3,
                                  int n4) {
    const float* s = (blockIdx.y == 0) ? s0 : (blockIdx.y == 1) ? s1
                    : (blockIdx.y == 2) ? s2 : s3;
    __bf16* d = (blockIdx.y == 0) ? d0 : (blockIdx.y == 1) ? d1
               : (blockIdx.y == 2) ? d2 : d3;
    int i = blockIdx.x * blockDim.x + threadIdx.x;
    const int stride = gridDim.x * blockDim.x;
    for (; i < n4; i += stride) {
        float4 f = ((const float4*)s)[i];
        bf16x4 o;
        o[0] = (__bf16)f.x; o[1] = (__bf16)f.y; o[2] = (__bf16)f.z; o[3] = (__bf16)f.w;
        ((bf16x4*)d)[i] = o;
    }
}

// Q, K, V activations in one launch (z selects tensor)
__global__ void cast3_f32_to_bf16(const float* __restrict__ s0, __bf16* __restrict__ d0,
                                  const float* __restrict__ s1, __bf16* __restrict__ d1,
                                  const float* __restrict__ s2, __bf16* __restrict__ d2,
                                  int n4) {
    const float* s = (blockIdx.y == 0) ? s0 : (blockIdx.y == 1) ? s1 : s2;
    __bf16* d = (blockIdx.y == 0) ? d0 : (blockIdx.y == 1) ? d1 : d2;
    int i = blockIdx.x * blockDim.x + threadIdx.x;
    const int stride = gridDim.x * blockDim.x;
    for (; i < n4; i += stride) {
        float4 f = ((const float4*)s)[i];
        bf16x4 o;
        o[0] = (__bf16)f.x; o[1] = (__bf16)f.y; o[2] = (__bf16)f.z; o[3] = (__bf16)f.w;
        ((bf16x4*)d)[i] = o;
    }
}

// ---------------------------------------------------------------------------
// C[8192,1024] = A[8192,1024] * Bt[1024,1024]^T   (Bt stored [N,K] row-major)
// MODE 1: f32 out, natural [m,n]  (used for the final WO projection)
template<int MODE>
__global__ __launch_bounds__(256, 2) void gemm_bt(const __bf16* __restrict__ A,
                                                  const __bf16* __restrict__ Bt,
                                                  void* __restrict__ out,
                                                  float scale)
{
    __shared__ __bf16 As[128 * 32];
    __shared__ __bf16 Bs[128 * 32];
    const int tid  = threadIdx.x;
    const int lane = tid & 63;
    const int u = lane >> 4, v = lane & 15;
    const int w = tid >> 6;
    const int wm = (w >> 1) * 64, wn = (w & 1) * 64;
    const long tM = (long)blockIdx.y * 128;
    const int  tN = blockIdx.x * 128;

    f32x4 acc[4][4];
#pragma unroll
    for (int i = 0; i < 4; ++i)
#pragma unroll
        for (int j = 0; j < 4; ++j) acc[i][j] = (f32x4){0.f, 0.f, 0.f, 0.f};

    const int c0 = tid, c1 = tid + 256;
    const int ar0 = c0 >> 2, ak0 = (c0 & 3) * 8;
    const int ar1 = c1 >> 2, ak1 = (c1 & 3) * 8;

    const __bf16* Ab = A  + tM * 1024;
    const __bf16* Bb = Bt + (long)tN * 1024;

    for (int k0 = 0; k0 < 1024; k0 += 32) {
        __syncthreads();
        cp16(&As[ar0 * 32 + ak0], Ab + (long)ar0 * 1024 + k0 + ak0);
        cp16(&As[ar1 * 32 + ak1], Ab + (long)ar1 * 1024 + k0 + ak1);
        cp16(&Bs[ar0 * 32 + ak0], Bb + (long)ar0 * 1024 + k0 + ak0);
        cp16(&Bs[ar1 * 32 + ak1], Bb + (long)ar1 * 1024 + k0 + ak1);
        __syncthreads();

        bf16x8 af[4], bfr[4];
#pragma unroll
        for (int i = 0; i < 4; ++i)
            af[i] = *(const bf16x8*)&As[(wm + i * 16 + v) * 32 + u * 8];
#pragma unroll
        for (int j = 0; j < 4; ++j)
            bfr[j] = *(const bf16x8*)&Bs[(wn + j * 16 + v) * 32 + u * 8];
#pragma unroll
        for (int i = 0; i < 4; ++i)
#pragma unroll
            for (int j = 0; j < 4; ++j)
                acc[i][j] = mfma16(af[i], bfr[j], acc[i][j]);
    }

#pragma unroll
    for (int i = 0; i < 4; ++i) {
#pragma unroll
        for (int j = 0; j < 4; ++j) {
            const long row0 = tM + wm + i * 16 + u * 4;
            const int  col  = tN + wn + j * 16 + v;
            if (MODE == 1) {
                float* o = (float*)out;
#pragma unroll
                for (int r = 0; r < 4; ++r)
                    o[(row0 + r) * 1024 + col] = acc[i][j][r];
            } else {
                __bf16* o = (__bf16*)out;
#pragma unroll
                for (int r = 0; r < 4; ++r)
                    o[(row0 + r) * 1024 + col] = (__bf16)(acc[i][j][r] * scale);
            }
        }
    }
}

// ---------------------------------------------------------------------------
// Batched Q/K/V projection: grid.z selects (A, Bt, out, mode).
// z=0: qp = (Xq WQ^T)*qscale   (natural bf16)
// z=1: kp =  Xk WK^T           (natural bf16)
// z=2: vt =  Xv WV^T           v-transposed [b,h,dh,s] bf16
__global__ __launch_bounds__(256, 2) void qkv_proj(
    const __bf16* __restrict__ xq, const __bf16* __restrict__ xk,
    const __bf16* __restrict__ xv,
    const __bf16* __restrict__ wq, const __bf16* __restrict__ wk,
    const __bf16* __restrict__ wv,
    __bf16* __restrict__ qp, __bf16* __restrict__ kp, __bf16* __restrict__ vtb,
    float qscale)
{
    __shared__ __bf16 As[128 * 32];
    __shared__ __bf16 Bs[128 * 32];
    const int z = blockIdx.z;
    const __bf16* A  = (z == 0) ? xq : (z == 1) ? xk : xv;
    const __bf16* Bt = (z == 0) ? wq : (z == 1) ? wk : wv;
    __bf16* out      = (z == 0) ? qp : (z == 1) ? kp : vtb;
    const float scale = (z == 0) ? qscale : 1.0f;

    const int tid  = threadIdx.x;
    const int lane = tid & 63;
    const int u = lane >> 4, v = lane & 15;
    const int w = tid >> 6;
    const int wm = (w >> 1) * 64, wn = (w & 1) * 64;
    const long tM = (long)blockIdx.y * 128;
    const int  tN = blockIdx.x * 128;

    f32x4 acc[4][4];
#pragma unroll
    for (int i = 0; i < 4; ++i)
#pragma unroll
        for (int j = 0; j < 4; ++j) acc[i][j] = (f32x4){0.f, 0.f, 0.f, 0.f};

    const int c0 = tid, c1 = tid + 256;
    const int ar0 = c0 >> 2, ak0 = (c0 & 3) * 8;
    const int ar1 = c1 >> 2, ak1 = (c1 & 3) * 8;

    const __bf16* Ab = A  + tM * 1024;
    const __bf16* Bb = Bt + (long)tN * 1024;

    for (int k0 = 0; k0 < 1024; k0 += 32) {
        __syncthreads();
        cp16(&As[ar0 * 32 + ak0], Ab + (long)ar0 * 1024 + k0 + ak0);
        cp16(&As[ar1 * 32 + ak1], Ab + (long)ar1 * 1024 + k0 + ak1);
        cp16(&Bs[ar0 * 32 + ak0], Bb + (long)ar0 * 1024 + k0 + ak0);
        cp16(&Bs[ar1 * 32 + ak1], Bb + (long)ar1 * 1024 + k0 + ak1);
        __syncthreads();

        bf16x8 af[4], bfr[4];
#pragma unroll
        for (int i = 0; i < 4; ++i)
            af[i] = *(const bf16x8*)&As[(wm + i * 16 + v) * 32 + u * 8];
#pragma unroll
        for (int j = 0; j < 4; ++j)
            bfr[j] = *(const bf16x8*)&Bs[(wn + j * 16 + v) * 32 + u * 8];
#pragma unroll
        for (int i = 0; i < 4; ++i)
#pragma unroll
            for (int j = 0; j < 4; ++j)
                acc[i][j] = mfma16(af[i], bfr[j], acc[i][j]);
    }

#pragma unroll
    for (int i = 0; i < 4; ++i) {
#pragma unroll
        for (int j = 0; j < 4; ++j) {
            const long row0 = tM + wm + i * 16 + u * 4;
            const int  col  = tN + wn + j * 16 + v;
            if (z < 2) {
#pragma unroll
                for (int r = 0; r < 4; ++r)
                    out[(row0 + r) * 1024 + col] = (__bf16)(acc[i][j][r] * scale);
            } else {
                const int bidx = (int)(row0 >> 11);
                const int s    = (int)(row0 & 2047);          // 4-aligned
                const int h = col >> 7, dh = col & 127;
                bf16x4 pk;
#pragma unroll
                for (int r = 0; r < 4; ++r) pk[r] = (__bf16)acc[i][j][r];
                *(bf16x4*)&out[((long)(bidx * 8 + h) * 128 + dh) * 2048 + s] = pk;
            }
        }
    }
}

// ---------------------------------------------------------------------------
// qk_head_softmax v4: one (b, 64k x 128q) tile, all 8 heads, two passes.
// BK=64 staging (16 MFMA per barrier-pair), XOR-swizzled LDS:
//  - As/Bs: LDS[r][c] holds global chunk (c ^ (r&7))  (16B chunk units);
//    cp16 dest stays linear (byte = 16*tid), global SOURCE is swizzled.
//  - frag reads XOR the chunk index with (v&7); tb transpose buffer XORs
//    with (row&7) on both write and read (involution -> bijective).
// LDS = 8 + 16 + 16 = 40 KB exactly -> 4 blocks/CU.
__global__ __launch_bounds__(256, 4) void qk_head_softmax(
    const __bf16* __restrict__ kp, const __bf16* __restrict__ qp,
    __bf16* __restrict__ P, int b_base, int q_base)
{
    __shared__ __bf16 As[64 * 64];     // 8 KB   (K tile,  BK=64)
    __shared__ __bf16 Bs[128 * 64];    // 16 KB  (Q tile,  BK=64)
    __shared__ __bf16 tb[128 * 64];    // 16 KB  transpose buffer (swizzled)
    const int tid  = threadIdx.x;
    const int lane = tid & 63;
    const int u = lane >> 4, v = lane & 15;
    const int w = tid >> 6;
    const int wm = (w >> 1) * 32, wn = (w & 1) * 64;   // 2x2 waves, 64k x 128q
    const int bloc = blockIdx.z;
    const int b    = b_base + bloc;
    const int k0   = blockIdx.x * 64;             // M-tile = 64 keys
    const int q0l  = blockIdx.y * 128;            // N-tile = 128 queries (local)
    const int q0g  = q_base + q0l;
    const long Cq  = (long)gridDim.y * 128;

    // staging: 16B chunks, 8 chunks per 64-elem row.
    // As: 512 chunks (2/thread), Bs: 1024 chunks (4/thread).
    const int sr = tid >> 3;           // base row 0..31
    const int sc = tid & 7;            // chunk-in-row

    const __bf16* Ka = kp + ((long)b * 2048 + k0) * 1024;
    const __bf16* Qa = qp + ((long)b * 2048 + q0g) * 1024;

    f32x4 den[2][4];
#pragma unroll
    for (int i = 0; i < 2; ++i)
#pragma unroll
        for (int j = 0; j < 4; ++j) den[i][j] = (f32x4){0.f, 0.f, 0.f, 0.f};

    // ---- pass 1: denominator only ----
#pragma unroll 1
    for (int h = 0; h < 8; ++h) {
        f32x4 acc[2][4];
#pragma unroll
        for (int i = 0; i < 2; ++i)
#pragma unroll
            for (int j = 0; j < 4; ++j) acc[i][j] = (f32x4){0.f, 0.f, 0.f, 0.f};

#pragma unroll
        for (int kb = 0; kb < 2; ++kb) {
            const int co = h * 128 + kb * 64;
            __syncthreads();
#pragma unroll
            for (int t = 0; t < 2; ++t) {
                const int r = sr + 32 * t;
                cp16(&As[r * 64 + sc * 8],
                     Ka + (long)r * 1024 + co + (sc ^ (r & 7)) * 8);
            }
#pragma unroll
            for (int t = 0; t < 4; ++t) {
                const int r = sr + 32 * t;
                cp16(&Bs[r * 64 + sc * 8],
                     Qa + (long)r * 1024 + co + (sc ^ (r & 7)) * 8);
            }
            __syncthreads();

#pragma unroll
            for (int ks = 0; ks < 2; ++ks) {
                bf16x8 af[2], bfr[4];
#pragma unroll
                for (int i = 0; i < 2; ++i) {
                    const int r = wm + i * 16 + v;
                    af[i] = *(const bf16x8*)&As[r * 64 +
                               ((ks * 32 + u * 8) ^ ((v & 7) * 8))];
                }
#pragma unroll
                for (int j = 0; j < 4; ++j) {
                    const int r = wn + j * 16 + v;
                    bfr[j] = *(const bf16x8*)&Bs[r * 64 +
                               ((ks * 32 + u * 8) ^ ((v & 7) * 8))];
                }
#pragma unroll
                for (int i = 0; i < 2; ++i)
#pragma unroll
                    for (int j = 0; j < 4; ++j)
                        acc[i][j] = mfma16(af[i], bfr[j], acc[i][j]);
            }
        }
#pragma unroll
        for (int i = 0; i < 2; ++i)
#pragma unroll
            for (int j = 0; j < 4; ++j)
#pragma unroll
                for (int r = 0; r < 4; ++r)
                    den[i][j][r] += __expf(acc[i][j][r]);
    }

    // rinv in place
#pragma unroll
    for (int i = 0; i < 2; ++i)
#pragma unroll
        for (int j = 0; j < 4; ++j)
#pragma unroll
            for (int r = 0; r < 4; ++r) den[i][j][r] = 1.0f / den[i][j][r];

    // ---- pass 2: recompute (bitwise-identical), normalize, store ----
#pragma unroll 1
    for (int h = 0; h < 8; ++h) {
        f32x4 acc[2][4];
#pragma unroll
        for (int i = 0; i < 2; ++i)
#pragma unroll
            for (int j = 0; j < 4; ++j) acc[i][j] = (f32x4){0.f, 0.f, 0.f, 0.f};

#pragma unroll
        for (int kb = 0; kb < 2; ++kb) {
            const int co = h * 128 + kb * 64;
            __syncthreads();
#pragma unroll
            for (int t = 0; t < 2; ++t) {
                const int r = sr + 32 * t;
                cp16(&As[r * 64 + sc * 8],
                     Ka + (long)r * 1024 + co + (sc ^ (r & 7)) * 8);
            }
#pragma unroll
            for (int t = 0; t < 4; ++t) {
                const int r = sr + 32 * t;
                cp16(&Bs[r * 64 + sc * 8],
                     Qa + (long)r * 1024 + co + (sc ^ (r & 7)) * 8);
            }
            __syncthreads();

#pragma unroll
            for (int ks = 0; ks < 2; ++ks) {
                bf16x8 af[2], bfr[4];
#pragma unroll
                for (int i = 0; i < 2; ++i) {
                    const int r = wm + i * 16 + v;
                    af[i] = *(const bf16x8*)&As[r * 64 +
                               ((ks * 32 + u * 8) ^ ((v & 7) * 8))];
                }
#pragma unroll
                for (int j = 0; j < 4; ++j) {
                    const int r = wn + j * 16 + v;
                    bfr[j] = *(const bf16x8*)&Bs[r * 64 +
                               ((ks * 32 + u * 8) ^ ((v & 7) * 8))];
                }
#pragma unroll
                for (int i = 0; i < 2; ++i)
#pragma unroll
                    for (int j = 0; j < 4; ++j)
                        acc[i][j] = mfma16(af[i], bfr[j], acc[i][j]);
            }
        }
        // normalize into swizzled LDS transpose buffer
        // (numerics: bf16(f32(bf16(e)) * rinv) -- identical to prior rounds)
        __syncthreads();   // prior head's tb reads complete
#pragma unroll
        for (int i = 0; i < 2; ++i)
#pragma unroll
            for (int j = 0; j < 4; ++j) {
                const int kc = wm + i * 16 + u * 4;   // key (tile-local, 0..63)
                const int qr = wn + j * 16 + v;       // query (tile-local)
                bf16x4 o;
#pragma unroll
                for (int r = 0; r < 4; ++r) {
                    float e = (float)(__bf16)__expf(acc[i][j][r]);
                    o[r] = (__bf16)(e * den[i][j][r]);
                }
                *(bf16x4*)&tb[qr * 64 + (kc ^ ((qr & 7) * 8))] = o;
            }
        __syncthreads();
        __bf16* Ph = P + ((long)(bloc * 8 + h) * Cq + q0l) * 2048 + k0;
#pragma unroll
        for (int p = 0; p < 4; ++p) {
            const int qq = p * 32 + (tid >> 3);       // 32 q-rows per pass
            const int kk = (tid & 7) * 8;             // 8 lanes x 16B = 128B row
            *(bf16x8*)&Ph[(long)qq * 2048 + kk] =
                *(const bf16x8*)&tb[qq * 64 + (kk ^ ((qq & 7) * 8))];
        }
    }
}

// ---------------------------------------------------------------------------
// ctxT[dh][q] = sum_k vt[b,h,dh,k] * P[bloc,h,q,k]  (Kdim=2048, 64 BK-iters)
// v4: 128dh x 64q tiles so a chunked launch still has >=512 blocks (2/CU).
// A = vt rows (dh, stride 2048), Bt = P rows (q, stride 2048, L3-resident).
// Epilogue stores ctx in concat layout [b][q][h*128+dh] via bf16x4.
__global__ __launch_bounds__(256, 2) void pv_gemm(
    const __bf16* __restrict__ vt, const __bf16* __restrict__ P,
    __bf16* __restrict__ ctx, int b_base, int q_base)
{
    __shared__ __bf16 As[128 * 32];   // vt tile, 8 KB
    __shared__ __bf16 Bs[64 * 32];    // P  tile, 4 KB
    const int tid  = threadIdx.x;
    const int lane = tid & 63;
    const int u = lane >> 4, v = lane & 15;
    const int w = tid >> 6;
    const int wm = (w >> 1) * 64, wn = (w & 1) * 32;  // 2x2 waves, 128dh x 64q
    const int bhl  = blockIdx.y;                  // bloc*8 + h
    const int bloc = bhl >> 3, h = bhl & 7;
    const int b    = b_base + bloc;
    const int q0l  = blockIdx.x * 64;
    const int q0g  = q_base + q0l;
    const long Cq  = (long)gridDim.x * 64;

    const int ar0 = tid >> 2, ak = (tid & 3) * 8;   // As: 2 chunks/thread
    // Bs: 1 chunk/thread (rows 0..63)

    const __bf16* Ab = vt + (long)(b * 8 + h) * 128 * 2048;
    const __bf16* Bb = P  + ((long)(bloc * 8 + h) * Cq + q0l) * 2048;

    f32x4 acc[4][2];
#pragma unroll
    for (int i = 0; i < 4; ++i)
#pragma unroll
        for (int j = 0; j < 2; ++j) acc[i][j] = (f32x4){0.f, 0.f, 0.f, 0.f};

    for (int k0 = 0; k0 < 2048; k0 += 32) {
        __syncthreads();
        cp16(&As[ar0 * 32 + ak], Ab + (long)ar0 * 2048 + k0 + ak);
        cp16(&As[(ar0 + 64) * 32 + ak], Ab + (long)(ar0 + 64) * 2048 + k0 + ak);
        cp16(&Bs[ar0 * 32 + ak], Bb + (long)ar0 * 2048 + k0 + ak);
        __syncthreads();

        bf16x8 af[4], bfr[2];
#pragma unroll
        for (int i = 0; i < 4; ++i)
            af[i] = *(const bf16x8*)&As[(wm + i * 16 + v) * 32 + u * 8];
#pragma unroll
        for (int j = 0; j < 2; ++j)
            bfr[j] = *(const bf16x8*)&Bs[(wn + j * 16 + v) * 32 + u * 8];
#pragma unroll
        for (int i = 0; i < 4; ++i)
#pragma unroll
            for (int j = 0; j < 2; ++j)
                acc[i][j] = mfma16(af[i], bfr[j], acc[i][j]);
    }

#pragma unroll
    for (int i = 0; i < 4; ++i) {
#pragma unroll
        for (int j = 0; j < 2; ++j) {
            const int dh0 = wm + i * 16 + u * 4;          // 4-consec feature
            const int q   = q0g + wn + j * 16 + v;
            bf16x4 pk;
#pragma unroll
            for (int r = 0; r < 4; ++r) pk[r] = (__bf16)acc[i][j][r];
            *(bf16x4*)&ctx[((long)b * 2048 + q) * 1024 + h * 128 + dh0] = pk;
        }
    }
}

// ---------------------------------------------------------------------------
// Fallback (round-1 fused attention) if ws can't hold even the smallest P.
__global__ __launch_bounds__(256, 2) void attn_softmax_head(
    const __bf16* __restrict__ qp, const __bf16* __restrict__ kp,
    const __bf16* __restrict__ vt, __bf16* __restrict__ ctx)
{
    __shared__ float part[8 * 256];
    __shared__ float pb[4][2][16 * 33];

    const int tid  = threadIdx.x;
    const int lane = tid & 63;
    const int w = tid >> 6;
    const int u = lane >> 4, v = lane & 15;
    const int b  = blockIdx.y;
    const int q0 = blockIdx.x * 16;

    const long qoff = ((long)b * 2048 + q0 + v) * 1024;
    bf16x8 qf[2][4];
#pragma unroll
    for (int hh = 0; hh < 2; ++hh) {
        const int h = 2 * w + hh;
#pragma unroll
        for (int kk = 0; kk < 4; ++kk)
            qf[hh][kk] = *(const bf16x8*)(qp + qoff + h * 128 + kk * 32 + u * 8);
    }

    f32x4 acc[2][8];
#pragma unroll
    for (int hh = 0; hh < 2; ++hh)
#pragma unroll
        for (int dt = 0; dt < 8; ++dt) acc[hh][dt] = (f32x4){0.f, 0.f, 0.f, 0.f};

    for (int kt = 0; kt < 2048; kt += 32) {
        float e[2][2][4];
#pragma unroll
        for (int hh = 0; hh < 2; ++hh) {
            const int h = 2 * w + hh;
#pragma unroll
            for (int t = 0; t < 2; ++t) {
                f32x4 s = (f32x4){0.f, 0.f, 0.f, 0.f};
                const __bf16* kb = kp + ((long)b * 2048 + kt + t * 16 + v) * 1024
                                      + h * 128 + u * 8;
#pragma unroll
                for (int kk = 0; kk < 4; ++kk)
                    s = mfma16(*(const bf16x8*)(kb + kk * 32), qf[hh][kk], s);
#pragma unroll
                for (int r = 0; r < 4; ++r) e[hh][t][r] = __expf(s[r]);
            }
        }
#pragma unroll
        for (int t = 0; t < 2; ++t)
#pragma unroll
            for (int r = 0; r < 4; ++r)
                part[(t * 4 + r) * 256 + w * 64 + lane] = e[0][t][r] + e[1][t][r];
        __syncthreads();
#pragma unroll
        for (int t = 0; t < 2; ++t)
#pragma unroll
            for (int r = 0; r < 4; ++r) {
                const int j = (t * 4 + r) * 256 + lane;
                const float den = part[j] + part[j + 64] + part[j + 128] + part[j + 192];
                const float rinv = 1.0f / den;
                const int kl = t * 16 + u * 4 + r;
                pb[w][0][v * 33 + kl] = e[0][t][r] * rinv;
                pb[w][1][v * 33 + kl] = e[1][t][r] * rinv;
            }
        bf16x8 pf[2];
#pragma unroll
        for (int hh = 0; hh < 2; ++hh)
#pragma unroll
            for (int jj = 0; jj < 8; ++jj)
                pf[hh][jj] = (__bf16)pb[w][hh][v * 33 + u * 8 + jj];
#pragma unroll
        for (int hh = 0; hh < 2; ++hh) {
            const int h = 2 * w + hh;
            const __bf16* vb = vt + ((long)(b * 8 + h) * 128 + v) * 2048 + kt + u * 8;
#pragma unroll
            for (int dt = 0; dt < 8; ++dt)
                acc[hh][dt] = mfma16(*(const bf16x8*)(vb + (long)dt * 16 * 2048),
                                     pf[hh], acc[hh][dt]);
        }
        __syncthreads();
    }

#pragma unroll
    for (int hh = 0; hh < 2; ++hh) {
        const int h = 2 * w + hh;
#pragma unroll
        for (int dt = 0; dt < 8; ++dt) {
            bf16x4 o;
#pragma unroll
            for (int r = 0; r < 4; ++r) o[r] = (__bf16)acc[hh][dt][r];
            *(bf16x4*)(ctx + ((long)b * 2048 + q0 + v) * 1024
                           + h * 128 + dt * 16 + u * 4) = o;
        }
    }
}

// ---------------------------------------------------------------------------
extern "C" void kernel_launch(void* const* d_in, const int* in_sizes, int n_in,
                              void* d_out, int out_size, void* d_ws, size_t ws_size,
                              hipStream_t stream)
{
    const float* Q  = (const float*)d_in[0];
    const float* K  = (const float*)d_in[1];
    const float* V  = (const float*)d_in[2];
    const float* WQ = (const float*)d_in[3];
    const float* WK = (const float*)d_in[4];
    const float* WV = (const float*)d_in[5];
    const float* WO = (const float*)d_in[6];

    // workspace layout (bf16 elems):
    //   4x 1M weights (8.4 MB) + 7x 8.4M tensors (117.4 MB) + chunked P
    __bf16* ws = (__bf16*)d_ws;
    __bf16* wq = ws;
    __bf16* wk = wq + 1048576;
    __bf16* wv = wk + 1048576;
    __bf16* wo = wv + 1048576;
    __bf16* xq = wo + 1048576;     // Q cast
    __bf16* xk = xq + 8388608;     // K cast
    __bf16* xv = xk + 8388608;     // V cast
    __bf16* qp = xv + 8388608;
    __bf16* kp = qp + 8388608;
    __bf16* vt = kp + 8388608;
    __bf16* xb = vt + 8388608;     // ctx
    __bf16* pbuf = xb + 8388608;   // P chunk buffer (size from ladder)

    const float qscale = 0.08838834764831845f;   // 1/sqrt(128)

    cast4_f32_to_bf16<<<dim3(256, 4), 256, 0, stream>>>(
        WQ, wq, WK, wk, WV, wv, WO, wo, 262144);
    cast3_f32_to_bf16<<<dim3(2048, 3), 256, 0, stream>>>(
        Q, xq, K, xk, V, xv, 2097152);
    qkv_proj<<<dim3(8, 64, 3), 256, 0, stream>>>(
        xq, xk, xv, wq, wk, wv, qp, kp, vt, qscale);

    // adaptive P sizing: (nb batches) x 8h x (C queries) x 2048 keys, bf16.
    // Preferred {4,1024}: 134 MB chunk -> L3-resident between qk and pv.
    const size_t baseBytes = 62914560ULL * 2ULL;          // 125.8 MB
    const size_t avail = (ws_size > baseBytes) ? ws_size - baseBytes : 0;
    const int cfgs[5][2] = {{4,1024},{4,512},{2,512},{1,512},{1,256}};
    int nb = 0, C = 0;
    for (int c = 0; c < 5; ++c) {
        const size_t need = (size_t)cfgs[c][0] * 8 * cfgs[c][1] * 2048 * 2;
        if (need <= avail) { nb = cfgs[c][0]; C = cfgs[c][1]; break; }
    }

    if (nb) {
        for (int bb = 0; bb < 4; bb += nb)
            for (int qq = 0; qq < 2048; qq += C) {
                qk_head_softmax<<<dim3(32, C / 128, nb), 256, 0, stream>>>(
                    kp, qp, pbuf, bb, qq);
                pv_gemm<<<dim3(C / 64, nb * 8), 256, 0, stream>>>(
                    vt, pbuf, xb, bb, qq);
            }
    } else {
        attn_softmax_head<<<dim3(128, 4), 256, 0, stream>>>(qp, kp, vt, xb);
    }

    gemm_bt<1><<<dim3(8, 64), 256, 0, stream>>>(xb, wo, (float*)d_out, 1.0f);
}